// Round 13
// baseline (157.761 us; speedup 1.0000x reference)
//
#include <hip/hip_runtime.h>

// ============================================================================
// ROUND-13 DIAGNOSTIC (clean): attn j-loop amplified x7 with the R7-proven
// rep-wrapper ONLY — loop body is the R11-proven code (builtin fexp2,
// perm-truncation pack). One layout-proof change: lsum via MFMA with an
// all-ones A fragment (D[r][c] = sum_k P[k][c] for ANY A-layout when A==1),
// deleting the per-js VALU adds and the shfl_xor reduction.
// Next round reverts ATTN_REPS to 1.
// ============================================================================
#define ATTN_REPS 7

typedef short bf16x4 __attribute__((ext_vector_type(4)));
typedef short bf16x8 __attribute__((ext_vector_type(8)));
typedef float f32x4 __attribute__((ext_vector_type(4)));
typedef unsigned short u16x4 __attribute__((ext_vector_type(4)));
typedef unsigned short u16x8 __attribute__((ext_vector_type(8)));

__device__ __forceinline__ unsigned short f2bf(float f) {
  union { float f; unsigned u; } v; v.f = f;
  unsigned r = v.u + 0x7FFFu + ((v.u >> 16) & 1u);
  return (unsigned short)(r >> 16);
}
__device__ __forceinline__ unsigned fbits(float f) {
  union { float f; unsigned u; } x; x.f = f; return x.u;
}
__device__ __forceinline__ float bfloat(unsigned u) {
  union { unsigned u; float f; } x; x.u = u; return x.f;
}
__device__ __forceinline__ float fexp2(float x) {
#if __has_builtin(__builtin_amdgcn_exp2f)
  return __builtin_amdgcn_exp2f(x);
#else
  return exp2f(x);
#endif
}
// RNE packed f32->2xbf16 (verified on gfx950; used in qkvT/proj since R8)
__device__ __forceinline__ unsigned cvt_pk_bf16(float a, float b) {
  unsigned r;
  asm("v_cvt_pk_bf16_f32 %0, %1, %2" : "=v"(r) : "v"(a), "v"(b));
  return r;
}
__device__ __forceinline__ f32x4 pv_mfma(bf16x4 a, bf16x4 b, f32x4 c) {
#if __has_builtin(__builtin_amdgcn_mfma_f32_16x16x16bf16_1k)
  return __builtin_amdgcn_mfma_f32_16x16x16bf16_1k(a, b, c, 0, 0, 0);
#else
  bf16x8 az = {a[0], a[1], a[2], a[3], 0, 0, 0, 0};
  bf16x8 bz = {b[0], b[1], b[2], b[3], 0, 0, 0, 0};
  return __builtin_amdgcn_mfma_f32_16x16x32_bf16(az, bz, c, 0, 0, 0);
#endif
}

// ---------- fused qkv: in-block X transpose+cast (LDS f32) + W cast + MFMA ----
__global__ __launch_bounds__(256)
void qkvT_kernel(const float* __restrict__ Xq, const float* __restrict__ Xkv,
                 const float* __restrict__ Wqkv, unsigned short* __restrict__ Y16)
{
  __shared__ float Xf[128][33];
  const int t = threadIdx.x;
  const int w = t >> 6, c = t & 15, g = (t & 63) >> 4;
  const int n0 = blockIdx.x * 32;
  const int ob = blockIdx.y;
  const float* X = (ob >= 2) ? Xkv : Xq;

  {
    const int kr = t >> 3;
    const int nc = (t & 7) * 4;
    #pragma unroll
    for (int pass = 0; pass < 4; ++pass) {
      int k = pass * 32 + kr;
      f32x4 v = *(const f32x4*)&X[k * 4096 + n0 + nc];
      Xf[k][nc + 0] = v[0];
      Xf[k][nc + 1] = v[1];
      Xf[k][nc + 2] = v[2];
      Xf[k][nc + 3] = v[3];
    }
  }

  union { unsigned u[4]; bf16x8 v; } af[4];
  {
    const float* wr = Wqkv + (ob * 64 + w * 16 + c) * 128;
    #pragma unroll
    for (int ks = 0; ks < 4; ++ks) {
      f32x4 v0 = *(const f32x4*)&wr[ks * 32 + g * 8];
      f32x4 v1 = *(const f32x4*)&wr[ks * 32 + g * 8 + 4];
      af[ks].u[0] = cvt_pk_bf16(v0[0], v0[1]);
      af[ks].u[1] = cvt_pk_bf16(v0[2], v0[3]);
      af[ks].u[2] = cvt_pk_bf16(v1[0], v1[1]);
      af[ks].u[3] = cvt_pk_bf16(v1[2], v1[3]);
    }
  }
  __syncthreads();

  union { unsigned u[4]; bf16x8 v; } bfr[2][4];
  #pragma unroll
  for (int s = 0; s < 2; ++s) {
    const int n = s * 16 + c;
    #pragma unroll
    for (int ks = 0; ks < 4; ++ks) {
      const int kb = ks * 32 + g * 8;
      #pragma unroll
      for (int m = 0; m < 4; ++m)
        bfr[s][ks].u[m] = cvt_pk_bf16(Xf[kb + 2 * m][n], Xf[kb + 2 * m + 1][n]);
    }
  }

  f32x4 acc[2] = {{0.f, 0.f, 0.f, 0.f}, {0.f, 0.f, 0.f, 0.f}};
  #pragma unroll
  for (int ks = 0; ks < 4; ++ks) {
    acc[0] = __builtin_amdgcn_mfma_f32_16x16x32_bf16(af[ks].v, bfr[0][ks].v, acc[0], 0, 0, 0);
    acc[1] = __builtin_amdgcn_mfma_f32_16x16x32_bf16(af[ks].v, bfr[1][ks].v, acc[1], 0, 0, 0);
  }
  #pragma unroll
  for (int s = 0; s < 2; ++s)
    #pragma unroll
    for (int i = 0; i < 4; ++i)
      Y16[(ob * 64 + w * 16 + 4 * g + i) * 4096 + n0 + s * 16 + c] = f2bf(acc[s][i]);
}

// ---------- depthwise 3x3 SAME, quarter-plane blocks ----------
__global__ __launch_bounds__(256)
void dwconv_kernel(const unsigned short* __restrict__ T16, const float* __restrict__ Wd,
                   const float* __restrict__ temp, unsigned short* __restrict__ Qt,
                   unsigned short* __restrict__ Kt, unsigned short* __restrict__ Vb)
{
  __shared__ float P[18 * 64];
  const int jc = blockIdx.x >> 2;
  const int qtr = blockIdx.x & 3;
  const int y0 = qtr * 16;
  const int t = threadIdx.x;
  const unsigned short* in = T16 + jc * 4096;
  #pragma unroll
  for (int i = 0; i < 5; ++i) {
    int idx = i * 256 + t;
    if (idx < 1152) {
      int row = idx >> 6, col = idx & 63;
      int sy = y0 - 1 + row;
      P[idx] = (sy >= 0 && sy < 64) ? bfloat((unsigned)in[sy * 64 + col] << 16) : 0.f;
    }
  }
  float w[9];
  #pragma unroll
  for (int k = 0; k < 9; ++k) w[k] = Wd[jc * 9 + k];
  const float scale = (jc < 128) ? temp[jc >> 5] * 1.4426950408889634f : 1.0f;
  __syncthreads();

  const int hh = (jc >> 5) & 3, dd = jc & 31;
  unsigned short* outT = (jc < 128 ? Qt : Kt) + hh * 4096 * 32 + dd;
  unsigned short* outV = Vb + (jc - 256) * 4096 + y0 * 64;
  const bool is_v = (jc >= 256);

  #pragma unroll
  for (int i = 0; i < 4; ++i) {
    int p = i * 256 + t;
    int yl = p >> 6, x = p & 63;
    float acc = 0.f;
    #pragma unroll
    for (int dy = 0; dy < 3; ++dy) {
      int base = (yl + dy) * 64 + x;
      if (x > 0)  acc += w[dy * 3 + 0] * P[base - 1];
      acc += w[dy * 3 + 1] * P[base];
      if (x < 63) acc += w[dy * 3 + 2] * P[base + 1];
    }
    unsigned short r = f2bf(acc * scale);
    if (is_v) outV[p] = r;
    else      outT[(y0 * 64 + p) * 32] = r;
  }
}

// ----------------------- flash attention (bf16 MFMA) -----------------------
// R11-proven loop body. lsum via MFMA with all-ones A fragment: every lane of
// lsA[s] holds sum_m P[m][q=s*16+c] (layout-proof: A==1 makes all rows equal).
// ATTN_REPS x j-loop (output-invariant: oh and lsA scale identically).
__global__ __launch_bounds__(1024, 4)
void attn_kernel(const unsigned short* __restrict__ Qt,
                 const unsigned short* __restrict__ Kt,
                 const unsigned short* __restrict__ Vb,
                 unsigned short* __restrict__ Oth, unsigned short* __restrict__ Otl)
{
  extern __shared__ __align__(16) char lds[];
  float* WS = (float*)lds;                 // 8 slots x 2048 f32 (64 KB)
  float* lf = (float*)(lds + 65536);       // [16][64] per-wave lsum (4 KB)
  const int t = threadIdx.x;
  const int wv = t >> 6;
  const int l = t & 63;
  const int c = l & 15, g = l >> 4;
  const int h = blockIdx.y;
  const int nq = blockIdx.x * 64;
  const int m0w = wv * 256;

  bf16x8 qf[4];
  #pragma unroll
  for (int s = 0; s < 4; ++s)
    qf[s] = *(const bf16x8*)&Qt[(h * 4096 + nq + s * 16 + c) * 32 + g * 8];

  f32x4 oh[4][2];
  f32x4 lsA[4];
  #pragma unroll
  for (int s = 0; s < 4; ++s) {
    oh[s][0] = (f32x4){0.f, 0.f, 0.f, 0.f};
    oh[s][1] = (f32x4){0.f, 0.f, 0.f, 0.f};
    lsA[s]   = (f32x4){0.f, 0.f, 0.f, 0.f};
  }
  const bf16x4 onesb = {16256, 16256, 16256, 16256};  // 4x bf16 1.0 (0x3F80)

  const unsigned short* Kb  = Kt + (h * 4096 + m0w + c) * 32 + g * 8;
  const unsigned short* Vb0 = Vb + (h * 32 + c) * 4096 + m0w + g * 4;
  const unsigned short* Vb1 = Vb0 + 16 * 4096;

  #pragma unroll 1
  for (int rep = 0; rep < ATTN_REPS; ++rep) {
    const unsigned short* Kbr = Kb;
    const unsigned short* V0r = Vb0;
    const unsigned short* V1r = Vb1;
    asm volatile("" : "+v"(Kbr), "+v"(V0r), "+v"(V1r));
    #pragma unroll 4
    for (int j = 0; j < 16; ++j) {
      bf16x8 kf = *(const bf16x8*)&Kbr[j * 512];
      bf16x4 vf0 = *(const bf16x4*)&V0r[j * 16];
      bf16x4 vf1 = *(const bf16x4*)&V1r[j * 16];
      #pragma unroll
      for (int s = 0; s < 4; ++s) {
        f32x4 z = {0.f, 0.f, 0.f, 0.f};
        f32x4 sv = __builtin_amdgcn_mfma_f32_16x16x32_bf16(kf, qf[s], z, 0, 0, 0);
        float e0 = fexp2(sv[0]);
        float e1 = fexp2(sv[1]);
        float e2 = fexp2(sv[2]);
        float e3 = fexp2(sv[3]);
        union { unsigned u[2]; bf16x4 v; } pu;
        pu.u[0] = __builtin_amdgcn_perm(fbits(e1), fbits(e0), 0x07060302);
        pu.u[1] = __builtin_amdgcn_perm(fbits(e3), fbits(e2), 0x07060302);
        lsA[s]   = pv_mfma(onesb, pu.v, lsA[s]);
        oh[s][0] = pv_mfma(vf0, pu.v, oh[s][0]);
        oh[s][1] = pv_mfma(vf1, pu.v, oh[s][1]);
      }
    }
  }

  // publish per-wave lsum (no shuffles: every lane holds colsum for q=s*16+c)
  if (l < 16) {
    #pragma unroll
    for (int s = 0; s < 4; ++s) lf[wv * 64 + s * 16 + l] = lsA[s][0];
  }
  // round 1: waves 8-15 publish oh into slots 0-7
  if (wv >= 8) {
    float* slot = WS + (wv - 8) * 2048;
    #pragma unroll
    for (int s = 0; s < 4; ++s)
      #pragma unroll
      for (int hf = 0; hf < 2; ++hf)
        *(f32x4*)&slot[(s * 2 + hf) * 256 + l * 4] = oh[s][hf];
  }
  __syncthreads();
  // waves 0-7 accumulate; waves 4-7 republish their updated partials
  if (wv < 8) {
    float* slot = WS + wv * 2048;
    #pragma unroll
    for (int s = 0; s < 4; ++s)
      #pragma unroll
      for (int hf = 0; hf < 2; ++hf)
        oh[s][hf] += *(const f32x4*)&slot[(s * 2 + hf) * 256 + l * 4];
    if (wv >= 4) {
      #pragma unroll
      for (int s = 0; s < 4; ++s)
        #pragma unroll
        for (int hf = 0; hf < 2; ++hf)
          *(f32x4*)&slot[(s * 2 + hf) * 256 + l * 4] = oh[s][hf];
    }
  }
  __syncthreads();
  // waves 0-3 accumulate slots 4-7, publish finals into slots 0-3
  if (wv < 4) {
    float* src = WS + (wv + 4) * 2048;
    float* dst = WS + wv * 2048;
    #pragma unroll
    for (int s = 0; s < 4; ++s)
      #pragma unroll
      for (int hf = 0; hf < 2; ++hf) {
        oh[s][hf] += *(const f32x4*)&src[(s * 2 + hf) * 256 + l * 4];
        *(f32x4*)&dst[(s * 2 + hf) * 256 + l * 4] = oh[s][hf];
      }
  }
  __syncthreads();

  // final: sum 4 slots + 16 lsum partials, normalize, coalesced bf16 hi/lo out
  #pragma unroll
  for (int e = t; e < 2048; e += 1024) {
    int q = e >> 5, d = e & 31;
    int s = q >> 4, cc = q & 15, hf = d >> 4, gg = (d & 15) >> 2, ii = d & 3;
    int off = (s * 2 + hf) * 256 + (gg * 16 + cc) * 4 + ii;
    float s4 = WS[off] + WS[2048 + off] + WS[4096 + off] + WS[6144 + off];
    float li = 0.f;
    #pragma unroll
    for (int ww = 0; ww < 16; ++ww) li += lf[ww * 64 + q];
    float val = s4 / li;
    unsigned short hi = f2bf(val);
    float hfv = bfloat((unsigned)hi << 16);
    int idx = (nq + q) * 128 + h * 32 + d;
    Oth[idx] = hi;
    Otl[idx] = f2bf(val - hfv);
  }
}

// ---------- proj GEMM, split-bf16, W cast folded in-block ----------
__global__ __launch_bounds__(256)
void gemm_proj_kernel(const unsigned short* __restrict__ Oth,
                      const unsigned short* __restrict__ Otl,
                      const float* __restrict__ Wp, float* __restrict__ Y)
{
  const int t = threadIdx.x;
  const int w = t >> 6, c = t & 15, g = (t & 63) >> 4;
  const int n0 = blockIdx.x * 32;
  const int o_base = blockIdx.y * 64 + w * 16;
  f32x4 acc0 = {0.f, 0.f, 0.f, 0.f}, acc1 = {0.f, 0.f, 0.f, 0.f};
  #pragma unroll
  for (int ks = 0; ks < 4; ++ks) {
    const int ko = ks * 32 + g * 8;
    const float* wr = Wp + (o_base + c) * 128 + ko;
    union { unsigned u[4]; bf16x8 v; } ah, al;
    #pragma unroll
    for (int m = 0; m < 2; ++m) {
      f32x4 v = *(const f32x4*)&wr[m * 4];
      #pragma unroll
      for (int p = 0; p < 2; ++p) {
        unsigned hw = cvt_pk_bf16(v[2 * p], v[2 * p + 1]);
        float h0 = bfloat(hw << 16);
        float h1 = bfloat(hw & 0xFFFF0000u);
        ah.u[m * 2 + p] = hw;
        al.u[m * 2 + p] = cvt_pk_bf16(v[2 * p] - h0, v[2 * p + 1] - h1);
      }
    }
    bf16x8 bh0 = *(const bf16x8*)&Oth[(n0 + c) * 128 + ko];
    bf16x8 bl0 = *(const bf16x8*)&Otl[(n0 + c) * 128 + ko];
    bf16x8 bh1 = *(const bf16x8*)&Oth[(n0 + 16 + c) * 128 + ko];
    bf16x8 bl1 = *(const bf16x8*)&Otl[(n0 + 16 + c) * 128 + ko];
    acc0 = __builtin_amdgcn_mfma_f32_16x16x32_bf16(al.v, bh0, acc0, 0, 0, 0);
    acc0 = __builtin_amdgcn_mfma_f32_16x16x32_bf16(ah.v, bl0, acc0, 0, 0, 0);
    acc0 = __builtin_amdgcn_mfma_f32_16x16x32_bf16(ah.v, bh0, acc0, 0, 0, 0);
    acc1 = __builtin_amdgcn_mfma_f32_16x16x32_bf16(al.v, bh1, acc1, 0, 0, 0);
    acc1 = __builtin_amdgcn_mfma_f32_16x16x32_bf16(ah.v, bl1, acc1, 0, 0, 0);
    acc1 = __builtin_amdgcn_mfma_f32_16x16x32_bf16(ah.v, bh1, acc1, 0, 0, 0);
  }
  #pragma unroll
  for (int i = 0; i < 4; ++i) {
    Y[(o_base + 4 * g + i) * 4096 + n0 + c] = acc0[i];
    Y[(o_base + 4 * g + i) * 4096 + n0 + 16 + c] = acc1[i];
  }
}

extern "C" void kernel_launch(void* const* d_in, const int* in_sizes, int n_in,
                              void* d_out, int out_size, void* d_ws, size_t ws_size,
                              hipStream_t stream) {
  const float* xq    = (const float*)d_in[0];
  const float* xkv   = (const float*)d_in[1];
  const float* wqkv  = (const float*)d_in[2];
  const float* wdw   = (const float*)d_in[3];
  const float* wproj = (const float*)d_in[4];
  const float* temp  = (const float*)d_in[5];
  float* out = (float*)d_out;

  char* ws = (char*)d_ws;
  unsigned short* t16 = (unsigned short*)ws;                 // 3 MB  [384][4096]
  unsigned short* qt  = (unsigned short*)(ws + 3145728);     // 1 MB  [4][4096][32]
  unsigned short* kt  = (unsigned short*)(ws + 4194304);     // 1 MB
  unsigned short* vb  = (unsigned short*)(ws + 5242880);     // 1 MB  [128][4096]
  unsigned short* oth = (unsigned short*)(ws + 6291456);     // 1 MB  [4096][128]
  unsigned short* otl = (unsigned short*)(ws + 7340032);     // 1 MB

  qkvT_kernel<<<dim3(128, 6), 256, 0, stream>>>(xq, xkv, wqkv, t16);
  dwconv_kernel<<<dim3(1536), 256, 0, stream>>>(t16, wdw, temp, qt, kt, vb);
  attn_kernel<<<dim3(64, 4), 1024, 69632, stream>>>(qt, kt, vb, oth, otl);
  gemm_proj_kernel<<<dim3(128, 2), 256, 0, stream>>>(oth, otl, wproj, out);
}

// Round 14
// 51.348 us; speedup vs baseline: 3.0724x; 3.0724x over previous
//
#include <hip/hip_runtime.h>

typedef short bf16x4 __attribute__((ext_vector_type(4)));
typedef short bf16x8 __attribute__((ext_vector_type(8)));
typedef float f32x4 __attribute__((ext_vector_type(4)));
typedef unsigned short u16x4 __attribute__((ext_vector_type(4)));
typedef unsigned short u16x8 __attribute__((ext_vector_type(8)));

__device__ __forceinline__ unsigned short f2bf(float f) {
  union { float f; unsigned u; } v; v.f = f;
  unsigned r = v.u + 0x7FFFu + ((v.u >> 16) & 1u);
  return (unsigned short)(r >> 16);
}
__device__ __forceinline__ unsigned fbits(float f) {
  union { float f; unsigned u; } x; x.f = f; return x.u;
}
__device__ __forceinline__ float bfloat(unsigned u) {
  union { unsigned u; float f; } x; x.u = u; return x.f;
}
__device__ __forceinline__ float fexp2(float x) {
#if __has_builtin(__builtin_amdgcn_exp2f)
  return __builtin_amdgcn_exp2f(x);
#else
  return exp2f(x);
#endif
}
// RNE packed f32->2xbf16 (verified on gfx950; used in qkvT/proj since R8)
__device__ __forceinline__ unsigned cvt_pk_bf16(float a, float b) {
  unsigned r;
  asm("v_cvt_pk_bf16_f32 %0, %1, %2" : "=v"(r) : "v"(a), "v"(b));
  return r;
}

// ---------- fused qkv: in-block X transpose+cast (LDS f32) + W cast + MFMA ----
__global__ __launch_bounds__(256)
void qkvT_kernel(const float* __restrict__ Xq, const float* __restrict__ Xkv,
                 const float* __restrict__ Wqkv, unsigned short* __restrict__ Y16)
{
  __shared__ float Xf[128][33];
  const int t = threadIdx.x;
  const int w = t >> 6, c = t & 15, g = (t & 63) >> 4;
  const int n0 = blockIdx.x * 32;
  const int ob = blockIdx.y;
  const float* X = (ob >= 2) ? Xkv : Xq;

  {
    const int kr = t >> 3;
    const int nc = (t & 7) * 4;
    #pragma unroll
    for (int pass = 0; pass < 4; ++pass) {
      int k = pass * 32 + kr;
      f32x4 v = *(const f32x4*)&X[k * 4096 + n0 + nc];
      Xf[k][nc + 0] = v[0];
      Xf[k][nc + 1] = v[1];
      Xf[k][nc + 2] = v[2];
      Xf[k][nc + 3] = v[3];
    }
  }

  union { unsigned u[4]; bf16x8 v; } af[4];
  {
    const float* wr = Wqkv + (ob * 64 + w * 16 + c) * 128;
    #pragma unroll
    for (int ks = 0; ks < 4; ++ks) {
      f32x4 v0 = *(const f32x4*)&wr[ks * 32 + g * 8];
      f32x4 v1 = *(const f32x4*)&wr[ks * 32 + g * 8 + 4];
      af[ks].u[0] = cvt_pk_bf16(v0[0], v0[1]);
      af[ks].u[1] = cvt_pk_bf16(v0[2], v0[3]);
      af[ks].u[2] = cvt_pk_bf16(v1[0], v1[1]);
      af[ks].u[3] = cvt_pk_bf16(v1[2], v1[3]);
    }
  }
  __syncthreads();

  union { unsigned u[4]; bf16x8 v; } bfr[2][4];
  #pragma unroll
  for (int s = 0; s < 2; ++s) {
    const int n = s * 16 + c;
    #pragma unroll
    for (int ks = 0; ks < 4; ++ks) {
      const int kb = ks * 32 + g * 8;
      #pragma unroll
      for (int m = 0; m < 4; ++m)
        bfr[s][ks].u[m] = cvt_pk_bf16(Xf[kb + 2 * m][n], Xf[kb + 2 * m + 1][n]);
    }
  }

  f32x4 acc[2] = {{0.f, 0.f, 0.f, 0.f}, {0.f, 0.f, 0.f, 0.f}};
  #pragma unroll
  for (int ks = 0; ks < 4; ++ks) {
    acc[0] = __builtin_amdgcn_mfma_f32_16x16x32_bf16(af[ks].v, bfr[0][ks].v, acc[0], 0, 0, 0);
    acc[1] = __builtin_amdgcn_mfma_f32_16x16x32_bf16(af[ks].v, bfr[1][ks].v, acc[1], 0, 0, 0);
  }
  #pragma unroll
  for (int s = 0; s < 2; ++s)
    #pragma unroll
    for (int i = 0; i < 4; ++i)
      Y16[(ob * 64 + w * 16 + 4 * g + i) * 4096 + n0 + s * 16 + c] = f2bf(acc[s][i]);
}

// ---------- depthwise 3x3 SAME, quarter-plane blocks ----------
__global__ __launch_bounds__(256)
void dwconv_kernel(const unsigned short* __restrict__ T16, const float* __restrict__ Wd,
                   const float* __restrict__ temp, unsigned short* __restrict__ Qt,
                   unsigned short* __restrict__ Kt, unsigned short* __restrict__ Vb)
{
  __shared__ float P[18 * 64];
  const int jc = blockIdx.x >> 2;
  const int qtr = blockIdx.x & 3;
  const int y0 = qtr * 16;
  const int t = threadIdx.x;
  const unsigned short* in = T16 + jc * 4096;
  #pragma unroll
  for (int i = 0; i < 5; ++i) {
    int idx = i * 256 + t;
    if (idx < 1152) {
      int row = idx >> 6, col = idx & 63;
      int sy = y0 - 1 + row;
      P[idx] = (sy >= 0 && sy < 64) ? bfloat((unsigned)in[sy * 64 + col] << 16) : 0.f;
    }
  }
  float w[9];
  #pragma unroll
  for (int k = 0; k < 9; ++k) w[k] = Wd[jc * 9 + k];
  const float scale = (jc < 128) ? temp[jc >> 5] * 1.4426950408889634f : 1.0f;
  __syncthreads();

  const int hh = (jc >> 5) & 3, dd = jc & 31;
  unsigned short* outT = (jc < 128 ? Qt : Kt) + hh * 4096 * 32 + dd;
  unsigned short* outV = Vb + (jc - 256) * 4096 + y0 * 64;
  const bool is_v = (jc >= 256);

  #pragma unroll
  for (int i = 0; i < 4; ++i) {
    int p = i * 256 + t;
    int yl = p >> 6, x = p & 63;
    float acc = 0.f;
    #pragma unroll
    for (int dy = 0; dy < 3; ++dy) {
      int base = (yl + dy) * 64 + x;
      if (x > 0)  acc += w[dy * 3 + 0] * P[base - 1];
      acc += w[dy * 3 + 1] * P[base];
      if (x < 63) acc += w[dy * 3 + 2] * P[base + 1];
    }
    unsigned short r = f2bf(acc * scale);
    if (is_v) outV[p] = r;
    else      outT[(y0 * 64 + p) * 32] = r;
  }
}

// ----------------------- flash attention (bf16 MFMA) -----------------------
// Real-K32 PV via k-slot relabeling: for a j-pair (j0,j1), k-slot 8g+e maps to
// key {j0-chunk 4g+e (e<4), j1-chunk 4g+e-4 (e>=4)}. The P B-frag is then
// exactly the 8 exps the lane already holds (zero cross-lane), and the V
// A-frag is the two b64 chunk-loads concatenated. Halves matrix-pipe work vs
// the zero-padded fallback (measured R13: matrix was the top consumer).
// lsum on VALU + shfl (R11-proven). Tree epilogue unchanged.
__global__ __launch_bounds__(1024, 4)
void attn_kernel(const unsigned short* __restrict__ Qt,
                 const unsigned short* __restrict__ Kt,
                 const unsigned short* __restrict__ Vb,
                 unsigned short* __restrict__ Oth, unsigned short* __restrict__ Otl)
{
  extern __shared__ __align__(16) char lds[];
  float* WS = (float*)lds;                 // 8 slots x 2048 f32 (64 KB)
  float* lf = (float*)(lds + 65536);       // [16][64] per-wave lsum (4 KB)
  const int t = threadIdx.x;
  const int wv = t >> 6;
  const int l = t & 63;
  const int c = l & 15, g = l >> 4;
  const int h = blockIdx.y;
  const int nq = blockIdx.x * 64;
  const int m0w = wv * 256;

  bf16x8 qf[4];
  #pragma unroll
  for (int s = 0; s < 4; ++s)
    qf[s] = *(const bf16x8*)&Qt[(h * 4096 + nq + s * 16 + c) * 32 + g * 8];

  f32x4 oh[4][2];
  #pragma unroll
  for (int s = 0; s < 4; ++s) {
    oh[s][0] = (f32x4){0.f, 0.f, 0.f, 0.f};
    oh[s][1] = (f32x4){0.f, 0.f, 0.f, 0.f};
  }
  float lsum[4] = {0.f, 0.f, 0.f, 0.f};

  const unsigned short* Kb  = Kt + (h * 4096 + m0w + c) * 32 + g * 8;
  const unsigned short* Vb0 = Vb + (h * 32 + c) * 4096 + m0w + g * 4;
  const unsigned short* Vb1 = Vb0 + 16 * 4096;

  #pragma unroll 2
  for (int jp = 0; jp < 8; ++jp) {
    const int j0 = jp * 2, j1 = jp * 2 + 1;
    bf16x8 kf0 = *(const bf16x8*)&Kb[j0 * 512];
    bf16x8 kf1 = *(const bf16x8*)&Kb[j1 * 512];
    // V A-frags: lane(c,g) -> {V[d][j0-chunk 4g..4g+3], V[d][j1-chunk 4g..4g+3]}
    bf16x4 va0 = *(const bf16x4*)&Vb0[j0 * 16];
    bf16x4 va1 = *(const bf16x4*)&Vb0[j1 * 16];
    bf16x4 vc0 = *(const bf16x4*)&Vb1[j0 * 16];
    bf16x4 vc1 = *(const bf16x4*)&Vb1[j1 * 16];
    bf16x8 vA = __builtin_shufflevector(va0, va1, 0, 1, 2, 3, 4, 5, 6, 7);
    bf16x8 vB = __builtin_shufflevector(vc0, vc1, 0, 1, 2, 3, 4, 5, 6, 7);
    #pragma unroll
    for (int s = 0; s < 4; ++s) {
      f32x4 z = {0.f, 0.f, 0.f, 0.f};
      f32x4 s0 = __builtin_amdgcn_mfma_f32_16x16x32_bf16(kf0, qf[s], z, 0, 0, 0);
      f32x4 s1 = __builtin_amdgcn_mfma_f32_16x16x32_bf16(kf1, qf[s], z, 0, 0, 0);
      float e00 = fexp2(s0[0]), e01 = fexp2(s0[1]);
      float e02 = fexp2(s0[2]), e03 = fexp2(s0[3]);
      float e10 = fexp2(s1[0]), e11 = fexp2(s1[1]);
      float e12 = fexp2(s1[2]), e13 = fexp2(s1[3]);
      lsum[s] += ((e00 + e01) + (e02 + e03)) + ((e10 + e11) + (e12 + e13));
      union { unsigned u[4]; bf16x8 v; } pu;
      pu.u[0] = __builtin_amdgcn_perm(fbits(e01), fbits(e00), 0x07060302);
      pu.u[1] = __builtin_amdgcn_perm(fbits(e03), fbits(e02), 0x07060302);
      pu.u[2] = __builtin_amdgcn_perm(fbits(e11), fbits(e10), 0x07060302);
      pu.u[3] = __builtin_amdgcn_perm(fbits(e13), fbits(e12), 0x07060302);
      oh[s][0] = __builtin_amdgcn_mfma_f32_16x16x32_bf16(vA, pu.v, oh[s][0], 0, 0, 0);
      oh[s][1] = __builtin_amdgcn_mfma_f32_16x16x32_bf16(vB, pu.v, oh[s][1], 0, 0, 0);
    }
  }

  // all 64 lanes hold the full wave lsum per query s*16+c after this
  #pragma unroll
  for (int s = 0; s < 4; ++s) {
    lsum[s] += __shfl_xor(lsum[s], 16, 64);
    lsum[s] += __shfl_xor(lsum[s], 32, 64);
  }

  // publish per-wave lsum once
  if (l < 16) {
    #pragma unroll
    for (int s = 0; s < 4; ++s) lf[wv * 64 + s * 16 + l] = lsum[s];
  }
  // round 1: waves 8-15 publish oh into slots 0-7
  if (wv >= 8) {
    float* slot = WS + (wv - 8) * 2048;
    #pragma unroll
    for (int s = 0; s < 4; ++s)
      #pragma unroll
      for (int hf = 0; hf < 2; ++hf)
        *(f32x4*)&slot[(s * 2 + hf) * 256 + l * 4] = oh[s][hf];
  }
  __syncthreads();
  // waves 0-7 accumulate; waves 4-7 republish their updated partials
  if (wv < 8) {
    float* slot = WS + wv * 2048;
    #pragma unroll
    for (int s = 0; s < 4; ++s)
      #pragma unroll
      for (int hf = 0; hf < 2; ++hf)
        oh[s][hf] += *(const f32x4*)&slot[(s * 2 + hf) * 256 + l * 4];
    if (wv >= 4) {
      #pragma unroll
      for (int s = 0; s < 4; ++s)
        #pragma unroll
        for (int hf = 0; hf < 2; ++hf)
          *(f32x4*)&slot[(s * 2 + hf) * 256 + l * 4] = oh[s][hf];
    }
  }
  __syncthreads();
  // waves 0-3 accumulate slots 4-7, publish finals into slots 0-3
  if (wv < 4) {
    float* src = WS + (wv + 4) * 2048;
    float* dst = WS + wv * 2048;
    #pragma unroll
    for (int s = 0; s < 4; ++s)
      #pragma unroll
      for (int hf = 0; hf < 2; ++hf) {
        oh[s][hf] += *(const f32x4*)&src[(s * 2 + hf) * 256 + l * 4];
        *(f32x4*)&dst[(s * 2 + hf) * 256 + l * 4] = oh[s][hf];
      }
  }
  __syncthreads();

  // final: sum 4 slots + 16 lsum partials, normalize, coalesced bf16 hi/lo out
  #pragma unroll
  for (int e = t; e < 2048; e += 1024) {
    int q = e >> 5, d = e & 31;
    int s = q >> 4, cc = q & 15, hf = d >> 4, gg = (d & 15) >> 2, ii = d & 3;
    int off = (s * 2 + hf) * 256 + (gg * 16 + cc) * 4 + ii;
    float s4 = WS[off] + WS[2048 + off] + WS[4096 + off] + WS[6144 + off];
    float li = 0.f;
    #pragma unroll
    for (int ww = 0; ww < 16; ++ww) li += lf[ww * 64 + q];
    float val = s4 / li;
    unsigned short hi = f2bf(val);
    float hfv = bfloat((unsigned)hi << 16);
    int idx = (nq + q) * 128 + h * 32 + d;
    Oth[idx] = hi;
    Otl[idx] = f2bf(val - hfv);
  }
}

// ---------- proj GEMM, split-bf16, W cast folded in-block ----------
__global__ __launch_bounds__(256)
void gemm_proj_kernel(const unsigned short* __restrict__ Oth,
                      const unsigned short* __restrict__ Otl,
                      const float* __restrict__ Wp, float* __restrict__ Y)
{
  const int t = threadIdx.x;
  const int w = t >> 6, c = t & 15, g = (t & 63) >> 4;
  const int n0 = blockIdx.x * 32;
  const int o_base = blockIdx.y * 64 + w * 16;
  f32x4 acc0 = {0.f, 0.f, 0.f, 0.f}, acc1 = {0.f, 0.f, 0.f, 0.f};
  #pragma unroll
  for (int ks = 0; ks < 4; ++ks) {
    const int ko = ks * 32 + g * 8;
    const float* wr = Wp + (o_base + c) * 128 + ko;
    union { unsigned u[4]; bf16x8 v; } ah, al;
    #pragma unroll
    for (int m = 0; m < 2; ++m) {
      f32x4 v = *(const f32x4*)&wr[m * 4];
      #pragma unroll
      for (int p = 0; p < 2; ++p) {
        unsigned hw = cvt_pk_bf16(v[2 * p], v[2 * p + 1]);
        float h0 = bfloat(hw << 16);
        float h1 = bfloat(hw & 0xFFFF0000u);
        ah.u[m * 2 + p] = hw;
        al.u[m * 2 + p] = cvt_pk_bf16(v[2 * p] - h0, v[2 * p + 1] - h1);
      }
    }
    bf16x8 bh0 = *(const bf16x8*)&Oth[(n0 + c) * 128 + ko];
    bf16x8 bl0 = *(const bf16x8*)&Otl[(n0 + c) * 128 + ko];
    bf16x8 bh1 = *(const bf16x8*)&Oth[(n0 + 16 + c) * 128 + ko];
    bf16x8 bl1 = *(const bf16x8*)&Otl[(n0 + 16 + c) * 128 + ko];
    acc0 = __builtin_amdgcn_mfma_f32_16x16x32_bf16(al.v, bh0, acc0, 0, 0, 0);
    acc0 = __builtin_amdgcn_mfma_f32_16x16x32_bf16(ah.v, bl0, acc0, 0, 0, 0);
    acc0 = __builtin_amdgcn_mfma_f32_16x16x32_bf16(ah.v, bh0, acc0, 0, 0, 0);
    acc1 = __builtin_amdgcn_mfma_f32_16x16x32_bf16(al.v, bh1, acc1, 0, 0, 0);
    acc1 = __builtin_amdgcn_mfma_f32_16x16x32_bf16(ah.v, bl1, acc1, 0, 0, 0);
    acc1 = __builtin_amdgcn_mfma_f32_16x16x32_bf16(ah.v, bh1, acc1, 0, 0, 0);
  }
  #pragma unroll
  for (int i = 0; i < 4; ++i) {
    Y[(o_base + 4 * g + i) * 4096 + n0 + c] = acc0[i];
    Y[(o_base + 4 * g + i) * 4096 + n0 + 16 + c] = acc1[i];
  }
}

extern "C" void kernel_launch(void* const* d_in, const int* in_sizes, int n_in,
                              void* d_out, int out_size, void* d_ws, size_t ws_size,
                              hipStream_t stream) {
  const float* xq    = (const float*)d_in[0];
  const float* xkv   = (const float*)d_in[1];
  const float* wqkv  = (const float*)d_in[2];
  const float* wdw   = (const float*)d_in[3];
  const float* wproj = (const float*)d_in[4];
  const float* temp  = (const float*)d_in[5];
  float* out = (float*)d_out;

  char* ws = (char*)d_ws;
  unsigned short* t16 = (unsigned short*)ws;                 // 3 MB  [384][4096]
  unsigned short* qt  = (unsigned short*)(ws + 3145728);     // 1 MB  [4][4096][32]
  unsigned short* kt  = (unsigned short*)(ws + 4194304);     // 1 MB
  unsigned short* vb  = (unsigned short*)(ws + 5242880);     // 1 MB  [128][4096]
  unsigned short* oth = (unsigned short*)(ws + 6291456);     // 1 MB  [4096][128]
  unsigned short* otl = (unsigned short*)(ws + 7340032);     // 1 MB

  qkvT_kernel<<<dim3(128, 6), 256, 0, stream>>>(xq, xkv, wqkv, t16);
  dwconv_kernel<<<dim3(1536), 256, 0, stream>>>(t16, wdw, temp, qt, kt, vb);
  attn_kernel<<<dim3(64, 4), 1024, 69632, stream>>>(qt, kt, vb, oth, otl);
  gemm_proj_kernel<<<dim3(128, 2), 256, 0, stream>>>(oth, otl, wproj, out);
}